// Round 3
// baseline (353.487 us; speedup 1.0000x reference)
//
#include <hip/hip_runtime.h>
#include <hip/hip_bf16.h>

typedef __bf16 bf16;
typedef __bf16 bf16x4 __attribute__((ext_vector_type(4)));
typedef __bf16 bf16x8 __attribute__((ext_vector_type(8)));
typedef float  f32x4  __attribute__((ext_vector_type(4)));

#define MFMA16(A,B,C) __builtin_amdgcn_mfma_f32_16x16x32_bf16((A),(B),(C),0,0,0)

constexpr int NI    = 64;     // instances
constexpr int NN    = 128;    // N (embedding rows / output cols)
constexpr int E     = 256;    // embed dim
constexpr int HID   = 1024;   // hidden
constexpr int BATCH = 2048;
constexpr int BM    = 128;    // batch rows per block
constexpr int BH    = 64;     // hidden chunk
constexpr int W1P   = E  + 8; // padded LDS rows
constexpr int W2P   = BH + 8;
constexpr int HP    = BH + 8;

__device__ __forceinline__ float fast_gelu(float x) {
    // tanh-form GELU: x * sigmoid(1.5957691*(x + 0.044715 x^3))
    float p = 1.5957691216f * __builtin_fmaf(0.044715f * x * x, x, x);
    return x * __builtin_amdgcn_rcpf(1.0f + __expf(-p));
}

// ---------------------------------------------------------------------------
// Fused MLP, single kernel, native fp32 weight layouts (no prepass).
// out[b,i,n] = gelu((embL[i,a1[b],:]+embR[i,a2[b],:]) @ W1[i]) @ W2[i]
// W1 = linear [NI][E][HID] f32, W2 = unembedding [NI][HID][NN] f32.
// Staging: per-thread 4x4 fp32 block -> register transpose + cvt -> ds_write_b64.
// Block: 256 thr = 4 waves; one (instance, 128-row batch tile); 16 hidden chunks.
// ---------------------------------------------------------------------------
__global__ __launch_bounds__(256, 2) void mlp3_fused(
    const int*   __restrict__ a,
    const float* __restrict__ embL,
    const float* __restrict__ embR,
    const float* __restrict__ W1,
    const float* __restrict__ W2,
    float* __restrict__ out)
{
    __shared__ __align__(16) bf16 sW1[BH][W1P];  // [h_local][e]   33792 B
    __shared__ __align__(16) bf16 sW2[NN][W2P];  // [n][h_local]   18432 B
    __shared__ __align__(16) bf16 sH [BM][HP];   // [row][h_local] 18432 B

    // XCD swizzle: consecutive blocks on one XCD share the instance -> weights L2-hot.
    const int blk   = blockIdx.x;
    const int xcd   = blk & 7;
    const int j     = blk >> 3;
    const int inst  = xcd + 8 * (j >> 4);
    const int btile = j & 15;

    const int tid  = threadIdx.x;
    const int wave = tid >> 6;
    const int lane = tid & 63;
    const int m = lane & 15;             // MFMA row/col within 16-tile
    const int q = lane >> 4;             // quad

    // ---- build A fragments (this wave's 32 rows x 256 e) in registers ----
    bf16x8 aF[2][8];
    #pragma unroll
    for (int rt = 0; rt < 2; ++rt) {
        const int r  = btile * BM + wave * 32 + rt * 16 + m;
        const int i1 = a[2 * r + 0];
        const int i2 = a[2 * r + 1];
        const float* pl = embL + ((size_t)inst * NN + i1) * E;
        const float* pr = embR + ((size_t)inst * NN + i2) * E;
        #pragma unroll
        for (int ks = 0; ks < 8; ++ks) {
            const int e0 = ks * 32 + q * 8;
            f32x4 l0 = *(const f32x4*)(pl + e0);
            f32x4 l1 = *(const f32x4*)(pl + e0 + 4);
            f32x4 r0 = *(const f32x4*)(pr + e0);
            f32x4 r1 = *(const f32x4*)(pr + e0 + 4);
            bf16x8 s;
            #pragma unroll
            for (int k = 0; k < 4; ++k) {
                s[k]     = (bf16)(l0[k] + r0[k]);
                s[k + 4] = (bf16)(l1[k] + r1[k]);
            }
            aF[rt][ks] = s;
        }
    }

    f32x4 O[2][8];
    #pragma unroll
    for (int rt = 0; rt < 2; ++rt)
        #pragma unroll
        for (int ct = 0; ct < 8; ++ct)
            O[rt][ct] = (f32x4){0.f, 0.f, 0.f, 0.f};

    // staging decomposition (per thread, per chunk):
    // W1 [e][h]: thread owns h0 = (tid&15)*4; e blocks e_base = s*64 + (tid>>4)*4
    const int w1_h0 = (tid & 15) * 4;
    const int w1_eq = (tid >> 4) * 4;
    // W2 [h][n]: thread owns n0 = (tid&31)*4; h blocks h_base = s2*32 + (tid>>5)*4
    const int w2_n0 = (tid & 31) * 4;
    const int w2_hq = (tid >> 5) * 4;

    #pragma unroll 1
    for (int c = 0; c < HID / BH; ++c) {
        __syncthreads();  // prev chunk's LDS reads done before restage

        // ---- stage W1 chunk: [e=0..255][h = c*64 .. +63] -> sW1[h][e] bf16 ----
        {
            const float* base = W1 + ((size_t)inst * E + w1_eq) * HID + c * BH + w1_h0;
            #pragma unroll
            for (int s = 0; s < 4; ++s) {
                f32x4 v[4];
                #pragma unroll
                for (int k = 0; k < 4; ++k)
                    v[k] = *(const f32x4*)(base + ((size_t)s * 64 + k) * HID);
                #pragma unroll
                for (int jj = 0; jj < 4; ++jj) {
                    bf16x4 w;
                    #pragma unroll
                    for (int k = 0; k < 4; ++k) w[k] = (bf16)v[k][jj];
                    *(bf16x4*)&sW1[w1_h0 + jj][s * 64 + w1_eq] = w;
                }
            }
        }
        // ---- stage W2 chunk: [h = c*64 .. +63][n=0..127] -> sW2[n][h] bf16 ----
        {
            const float* base = W2 + ((size_t)inst * HID + c * BH + w2_hq) * NN + w2_n0;
            #pragma unroll
            for (int s = 0; s < 2; ++s) {
                f32x4 v[4];
                #pragma unroll
                for (int k = 0; k < 4; ++k)
                    v[k] = *(const f32x4*)(base + ((size_t)s * 32 + k) * NN);
                #pragma unroll
                for (int jj = 0; jj < 4; ++jj) {
                    bf16x4 w;
                    #pragma unroll
                    for (int k = 0; k < 4; ++k) w[k] = (bf16)v[k][jj];
                    *(bf16x4*)&sW2[w2_n0 + jj][s * 32 + w2_hq] = w;
                }
            }
        }
        __syncthreads();

        // ---- GEMM1: S(32x64 per wave) = A @ W1c ----
        f32x4 S[2][4];
        #pragma unroll
        for (int rt = 0; rt < 2; ++rt)
            #pragma unroll
            for (int ct = 0; ct < 4; ++ct) S[rt][ct] = (f32x4){0.f, 0.f, 0.f, 0.f};
        #pragma unroll
        for (int ks = 0; ks < 8; ++ks) {
            #pragma unroll
            for (int ct = 0; ct < 4; ++ct) {
                bf16x8 b = *(const bf16x8*)&sW1[ct * 16 + m][ks * 32 + q * 8];
                S[0][ct] = MFMA16(aF[0][ks], b, S[0][ct]);
                S[1][ct] = MFMA16(aF[1][ks], b, S[1][ct]);
            }
        }

        // ---- GELU, C/D-layout -> wave-private LDS rows ----
        #pragma unroll
        for (int rt = 0; rt < 2; ++rt)
            #pragma unroll
            for (int ct = 0; ct < 4; ++ct)
                #pragma unroll
                for (int rr = 0; rr < 4; ++rr)
                    sH[wave * 32 + rt * 16 + q * 4 + rr][ct * 16 + m] =
                        (bf16)fast_gelu(S[rt][ct][rr]);
        asm volatile("s_waitcnt lgkmcnt(0)" ::: "memory");  // own-wave RAW on sH

        // ---- GEMM2: O += gelu(H) @ W2c ----
        #pragma unroll
        for (int k2 = 0; k2 < 2; ++k2) {
            bf16x8 h0 = *(const bf16x8*)&sH[wave * 32 +  0 + m][k2 * 32 + q * 8];
            bf16x8 h1 = *(const bf16x8*)&sH[wave * 32 + 16 + m][k2 * 32 + q * 8];
            #pragma unroll
            for (int ct = 0; ct < 8; ++ct) {
                bf16x8 b = *(const bf16x8*)&sW2[ct * 16 + m][k2 * 32 + q * 8];
                O[0][ct] = MFMA16(h0, b, O[0][ct]);
                O[1][ct] = MFMA16(h1, b, O[1][ct]);
            }
        }
    }

    // ---- epilogue: out[b, inst, n] fp32 ----
    #pragma unroll
    for (int rt = 0; rt < 2; ++rt)
        #pragma unroll
        for (int ct = 0; ct < 8; ++ct)
            #pragma unroll
            for (int rr = 0; rr < 4; ++rr) {
                const int b = btile * BM + wave * 32 + rt * 16 + q * 4 + rr;
                const int n = ct * 16 + m;
                out[((size_t)b * NI + inst) * NN + n] = O[rt][ct][rr];
            }
}

extern "C" void kernel_launch(void* const* d_in, const int* in_sizes, int n_in,
                              void* d_out, int out_size, void* d_ws, size_t ws_size,
                              hipStream_t stream)
{
    const int*   a    = (const int*)d_in[0];
    const float* embL = (const float*)d_in[1];
    const float* embR = (const float*)d_in[2];
    const float* lin  = (const float*)d_in[3];   // [NI][E][HID] f32
    const float* une  = (const float*)d_in[4];   // [NI][HID][NN] f32
    float* out = (float*)d_out;

    const int nblocks = (BATCH / BM) * NI;  // 1024
    mlp3_fused<<<nblocks, 256, 0, stream>>>(a, embL, embR, lin, une, out);
}